// Round 1
// 390.964 us; speedup vs baseline: 1.0047x; 1.0047x over previous
//
#include <hip/hip_runtime.h>
#include <math.h>

#define B  64
#define H  4
#define NN 16384
#define WD 64
#define DD 1024
#define PP 70   // W + 6

typedef float fx4 __attribute__((ext_vector_type(4)));  // native vec for nontemporal builtins

__device__ __forceinline__ float softplus_f(float x) {
    return fmaxf(x, 0.f) + log1pf(expf(-fabsf(x)));
}

// ---------------------------------------------------------------------------
// Kernel 1: params = state @ W_read.T + b_read, then activations.
// One block per (b,h). Outputs: kscaled[bh][64] = key * beta/max(||key||,eps),
// coef[bh][8] = {gate, sh0, sh1, sh2, gamma, beta}.
// State vector hoisted into registers once (reused across ~18 rows/wave).
// ---------------------------------------------------------------------------
__global__ __launch_bounds__(256) void k_params(
    const float* __restrict__ state, const float* __restrict__ Wr,
    const float* __restrict__ br, float* __restrict__ kscaled,
    float* __restrict__ coef)
{
    int bh = blockIdx.x;           // b*4 + h
    int b  = bh >> 2, h = bh & 3;
    int tid = threadIdx.x, wave = tid >> 6, lane = tid & 63;
    __shared__ float sp[PP];
    __shared__ float sbc[1];

    const float4* st4 = (const float4*)(state + (size_t)b * DD);
    float4 sv[4];
    #pragma unroll
    for (int q = 0; q < 4; ++q) sv[q] = st4[lane + 64 * q];

    for (int j = wave; j < PP; j += 4) {
        const float4* w4 = (const float4*)(Wr + (size_t)(h * PP + j) * DD);
        float acc = 0.f;
        #pragma unroll
        for (int q = 0; q < 4; ++q) {
            float4 wv = w4[lane + 64 * q];
            acc += wv.x * sv[q].x + wv.y * sv[q].y + wv.z * sv[q].z + wv.w * sv[q].w;
        }
        #pragma unroll
        for (int m = 32; m >= 1; m >>= 1) acc += __shfl_xor(acc, m, 64);
        if (lane == 0) sp[j] = acc + br[h * PP + j];
    }
    __syncthreads();
    if (tid == 0) {
        float ss = 0.f;
        for (int w = 0; w < WD; ++w) ss += sp[w] * sp[w];
        float knorm = fmaxf(sqrtf(ss), 1e-8f);
        float beta  = softplus_f(sp[64]);
        float gate  = 1.f / (1.f + expf(-sp[65]));
        float m3 = fmaxf(sp[66], fmaxf(sp[67], sp[68]));
        float e0 = expf(sp[66] - m3), e1 = expf(sp[67] - m3), e2 = expf(sp[68] - m3);
        float es = e0 + e1 + e2;
        float gamma = 1.f + softplus_f(sp[69]);
        float* c = coef + bh * 8;
        c[0] = gate; c[1] = e0 / es; c[2] = e1 / es; c[3] = e2 / es;
        c[4] = gamma; c[5] = beta;
        sbc[0] = beta / knorm;
    }
    __syncthreads();
    if (tid < WD) kscaled[bh * WD + tid] = sp[tid] * sbc[0];
}

// ---------------------------------------------------------------------------
// Kernel 2: e[b][h][n] = exp(beta*cos_sim - beta)  (softmax numerator shifted
// by the a-priori bound s<=beta; denominator recomputed in k_head).
// 128 rows/block, 32 rows/wave, 4 iters; ALL 8 loads issued up-front for MLP.
// Lane r=lane>>3 owns row, c=lane&7 owns 8 columns; 8-lane xor reductions.
// UNCHANGED from previous round (measured ~90%+ of achievable HBM BW).
// ---------------------------------------------------------------------------
__global__ __launch_bounds__(256) void k_sim(
    const float* __restrict__ mem, const float* __restrict__ kscaled,
    const float* __restrict__ coef, float* __restrict__ ebuf)
{
    int tid = threadIdx.x, wave = tid >> 6, lane = tid & 63;
    int blk = blockIdx.x;              // 8192 blocks
    int b = blk >> 7;                  // 128 blocks per batch
    int nblk = (blk & 127) * 128;      // 128 rows per block
    int r = lane >> 3, c = lane & 7;   // 8 rows x 8 col-groups

    const float* ksb = kscaled + b * 4 * WD + c * 8;
    float4 k0a = *(const float4*)(ksb + 0 * WD);
    float4 k0b = *(const float4*)(ksb + 0 * WD + 4);
    float4 k1a = *(const float4*)(ksb + 1 * WD);
    float4 k1b = *(const float4*)(ksb + 1 * WD + 4);
    float4 k2a = *(const float4*)(ksb + 2 * WD);
    float4 k2b = *(const float4*)(ksb + 2 * WD + 4);
    float4 k3a = *(const float4*)(ksb + 3 * WD);
    float4 k3b = *(const float4*)(ksb + 3 * WD + 4);

    float bet = (c < 4) ? coef[(b * 4 + c) * 8 + 5] : 0.f;

    int nw = nblk + wave * 32;
    // issue all 8 loads before any dependent compute (MLP)
    fx4 va[4], vb[4];
    #pragma unroll
    for (int it = 0; it < 4; ++it) {
        int n = nw + it * 8 + r;
        const fx4* rp = (const fx4*)(mem + ((size_t)b * NN + n) * WD + c * 8);
        va[it] = __builtin_nontemporal_load(rp);
        vb[it] = __builtin_nontemporal_load(rp + 1);
    }
    #pragma unroll
    for (int it = 0; it < 4; ++it) {
        fx4 v0 = va[it], v1 = vb[it];
        int n = nw + it * 8 + r;
        float d0 = v0.x*k0a.x + v0.y*k0a.y + v0.z*k0a.z + v0.w*k0a.w
                 + v1.x*k0b.x + v1.y*k0b.y + v1.z*k0b.z + v1.w*k0b.w;
        float d1 = v0.x*k1a.x + v0.y*k1a.y + v0.z*k1a.z + v0.w*k1a.w
                 + v1.x*k1b.x + v1.y*k1b.y + v1.z*k1b.z + v1.w*k1b.w;
        float d2 = v0.x*k2a.x + v0.y*k2a.y + v0.z*k2a.z + v0.w*k2a.w
                 + v1.x*k2b.x + v1.y*k2b.y + v1.z*k2b.z + v1.w*k2b.w;
        float d3 = v0.x*k3a.x + v0.y*k3a.y + v0.z*k3a.z + v0.w*k3a.w
                 + v1.x*k3b.x + v1.y*k3b.y + v1.z*k3b.z + v1.w*k3b.w;
        float q  = v0.x*v0.x + v0.y*v0.y + v0.z*v0.z + v0.w*v0.w
                 + v1.x*v1.x + v1.y*v1.y + v1.z*v1.z + v1.w*v1.w;
        #pragma unroll
        for (int m = 1; m < 8; m <<= 1) {
            d0 += __shfl_xor(d0, m, 64);
            d1 += __shfl_xor(d1, m, 64);
            d2 += __shfl_xor(d2, m, 64);
            d3 += __shfl_xor(d3, m, 64);
            q  += __shfl_xor(q,  m, 64);
        }
        if (c < 4) {
            float mn = fmaxf(sqrtf(q), 1e-8f);
            float d  = (c == 0) ? d0 : ((c == 1) ? d1 : ((c == 2) ? d2 : d3));
            ebuf[((size_t)(b * 4 + c)) * NN + n] = __expf(d / mn - bet);
        }
    }
}

// ---------------------------------------------------------------------------
// Kernel 3 (REWRITTEN): per (b,h) row: block-reduce denominator S, normalize,
// gate-mix, circular 3-tap shift, sharpen, renormalize.
// Thread t owns elements n = 4*(t + k*1024)+j, k=0..3, j=0..3:
//   - dwordx4 loads/stores, perfectly coalesced (1 KB per wave instruction)
//   - gated weights live in registers; shift is in-register except the two
//     edge elements per float4, exchanged via 32 KB LDS (ledge/redge)
//   - prev loaded nontemporal (read-once); out stored nontemporal (write-once)
// ---------------------------------------------------------------------------
__global__ __launch_bounds__(1024) void k_head(
    const float* __restrict__ ebuf, const float* __restrict__ prev,
    const float* __restrict__ coef, float* __restrict__ out)
{
    __shared__ float ledge[4][1024];
    __shared__ float redge[4][1024];
    __shared__ float redS[17];
    __shared__ float redT[17];
    int bh = blockIdx.x;
    int tid = threadIdx.x, wave = tid >> 6, lane = tid & 63;
    const fx4* erow = (const fx4*)(ebuf + (size_t)bh * NN);
    const fx4* prow = (const fx4*)(prev + (size_t)bh * NN);
    fx4* orow = (fx4*)(out + (size_t)bh * NN);
    const float* c = coef + bh * 8;
    float gate = c[0], sh0 = c[1], sh1 = c[2], sh2 = c[3], gamma = c[4];

    fx4 ev[4], pw[4];
    float ls = 0.f;
    #pragma unroll
    for (int k = 0; k < 4; ++k) {
        ev[k] = erow[tid + k * 1024];
        pw[k] = __builtin_nontemporal_load(prow + tid + k * 1024);
        ls += ev[k].x + ev[k].y + ev[k].z + ev[k].w;
    }
    #pragma unroll
    for (int d = 32; d >= 1; d >>= 1) ls += __shfl_xor(ls, d, 64);
    if (lane == 0) redS[wave] = ls;
    __syncthreads();
    if (tid == 0) {
        float x = 0.f;
        for (int i = 0; i < 16; ++i) x += redS[i];
        redS[16] = x;
    }
    __syncthreads();
    float S = redS[16];
    float ginvS = gate / S;
    float omg   = 1.f - gate;

    // gated weights in registers (overwrite ev), edges to LDS
    #pragma unroll
    for (int k = 0; k < 4; ++k) {
        ev[k] = ginvS * ev[k] + omg * pw[k];
        ledge[k][tid] = ev[k].x;
        redge[k][tid] = ev[k].w;
    }
    __syncthreads();

    // ---- shift + sharpen, all in registers ----
    fx4 sh[4];
    float ps = 0.f;
    #pragma unroll
    for (int k = 0; k < 4; ++k) {
        float gm1 = (tid == 0)    ? redge[(k + 3) & 3][1023] : redge[k][tid - 1];
        float gp1 = (tid == 1023) ? ledge[(k + 1) & 3][0]    : ledge[k][tid + 1];
        fx4 g = ev[k];
        float s0 = sh0 * gm1 + sh1 * g.x + sh2 * g.y;
        float s1 = sh0 * g.x + sh1 * g.y + sh2 * g.z;
        float s2 = sh0 * g.y + sh1 * g.z + sh2 * g.w;
        float s3 = sh0 * g.z + sh1 * g.w + sh2 * gp1;
        sh[k].x = __expf(gamma * __logf(s0));   // s* > 0 strictly
        sh[k].y = __expf(gamma * __logf(s1));
        sh[k].z = __expf(gamma * __logf(s2));
        sh[k].w = __expf(gamma * __logf(s3));
        ps += sh[k].x + sh[k].y + sh[k].z + sh[k].w;
    }
    #pragma unroll
    for (int d = 32; d >= 1; d >>= 1) ps += __shfl_xor(ps, d, 64);
    if (lane == 0) redT[wave] = ps;
    __syncthreads();
    if (tid == 0) {
        float x = 0.f;
        for (int i = 0; i < 16; ++i) x += redT[i];
        redT[16] = x;
    }
    __syncthreads();
    float T = redT[16] + 1e-6f;
    float invT = 1.f / T;
    #pragma unroll
    for (int k = 0; k < 4; ++k) {
        fx4 o = sh[k] * invT;
        __builtin_nontemporal_store(o, orow + tid + k * 1024);
    }
}

// ---------------------------------------------------------------------------
extern "C" void kernel_launch(void* const* d_in, const int* in_sizes, int n_in,
                              void* d_out, int out_size, void* d_ws, size_t ws_size,
                              hipStream_t stream) {
    const float* state = (const float*)d_in[0];   // (B, D)
    const float* prev  = (const float*)d_in[1];   // (B, H, N)
    const float* mem   = (const float*)d_in[2];   // (B, N, W)
    const float* Wr    = (const float*)d_in[3];   // (P*H, D)
    const float* br    = (const float*)d_in[4];   // (P*H,)
    float* out = (float*)d_out;                   // (B, H, N)

    float* ebuf    = (float*)d_ws;                     // B*H*N floats = 16 MB
    float* kscaled = ebuf + (size_t)B * H * NN;        // B*H*64 floats
    float* coef    = kscaled + (size_t)B * H * WD;     // B*H*8 floats

    k_params<<<B * H, 256, 0, stream>>>(state, Wr, br, kscaled, coef);
    k_sim<<<(B * NN) / 128, 256, 0, stream>>>(mem, kscaled, coef, ebuf);
    k_head<<<B * H, 1024, 0, stream>>>(ebuf, prev, coef, out);
}